// Round 11
// baseline (288.040 us; speedup 1.0000x reference)
//
#include <hip/hip_runtime.h>

#define BATCH 4
#define LSEQ  2048
#define DM    1024
#define NH    16
#define HD    64
#define NTOK  (BATCH * LSEQ)

typedef _Float16 f16x8 __attribute__((ext_vector_type(8)));
typedef _Float16 f16x4 __attribute__((ext_vector_type(4)));
typedef __fp16   hf16x2 __attribute__((ext_vector_type(2)));
typedef float    f32x4 __attribute__((ext_vector_type(4)));
typedef float    f32x16 __attribute__((ext_vector_type(16)));

typedef __attribute__((address_space(1))) const unsigned int GU32;
typedef __attribute__((address_space(3))) unsigned int LU32;

// async 16B/lane global->LDS. lptr must be wave-uniform; HW dest = lptr + lane*16.
__device__ __forceinline__ void gload_lds16(const _Float16* g, _Float16* l)
{
    __builtin_amdgcn_global_load_lds(
        (GU32*)(unsigned long long)g,
        (LU32*)(unsigned int)(unsigned long long)l, 16, 0, 0);
}

// ---------------------------------------------------------------------------
// Fused prep: one launch, three phases by linear block-id range (R10 verified).
// ---------------------------------------------------------------------------
__global__ __launch_bounds__(256) void prep_kernel(
    const float* __restrict__ x,
    const float* __restrict__ Wq, const float* __restrict__ Wk,
    const float* __restrict__ Wv, const float* __restrict__ Wo,
    _Float16* __restrict__ xh, _Float16* __restrict__ WtA,
    _Float16* __restrict__ Wot)
{
    const int bid = blockIdx.x;
    const int t = threadIdx.x;

    if (bid < 8192) {                       // ---- cvt phase ----
        int i = bid * 256 + t;
        float4 v = ((const float4*)x)[i];
        f16x4 h;
        h[0] = (_Float16)v.x; h[1] = (_Float16)v.y; h[2] = (_Float16)v.z; h[3] = (_Float16)v.w;
        ((f16x4*)xh)[i] = h;
        return;
    }

    __shared__ float Ls[64][65];

    if (bid < 8960) {                       // ---- Wq/Wk/Wv transpose ----
        const int idx = bid - 8192;
        const int z = idx >> 4;             // 0..47
        const int which = z >> 4, h = z & 15;
        const float* __restrict__ src =
            ((which == 0) ? Wq : (which == 1) ? Wk : Wv) + (size_t)h * DM * HD;
        _Float16* __restrict__ d = WtA + (size_t)z * DM * HD;
        const int e0 = (idx & 15) * 64;
        #pragma unroll
        for (int j = 0; j < 4; ++j) {
            int cidx = t + j * 256;
            int row = cidx >> 4, col4 = (cidx & 15) * 4;
            float4 v = *(const float4*)&src[(size_t)(e0 + row) * HD + col4];
            Ls[row][col4] = v.x; Ls[row][col4+1] = v.y; Ls[row][col4+2] = v.z; Ls[row][col4+3] = v.w;
        }
        __syncthreads();
        const int dd = t & 63, sc = t >> 6;
        alignas(16) _Float16 tmp[16];
        #pragma unroll
        for (int i = 0; i < 16; ++i) tmp[i] = (_Float16)Ls[sc * 16 + i][dd];
        *(f16x8*)&d[(size_t)dd * DM + e0 + sc * 16]     = *(f16x8*)&tmp[0];
        *(f16x8*)&d[(size_t)dd * DM + e0 + sc * 16 + 8] = *(f16x8*)&tmp[8];
        return;
    }

    {                                       // ---- Wo transpose ----
        const int idx = bid - 8960;
        const int d0 = (idx & 15) * 64, e0 = (idx >> 4) * 64;
        #pragma unroll
        for (int j = 0; j < 4; ++j) {
            int cidx = t + j * 256;
            int row = cidx >> 4, col4 = (cidx & 15) * 4;
            float4 v = *(const float4*)&Wo[(size_t)(e0 + row) * DM + d0 + col4];
            Ls[row][col4] = v.x; Ls[row][col4+1] = v.y; Ls[row][col4+2] = v.z; Ls[row][col4+3] = v.w;
        }
        __syncthreads();
        const int dd = t & 63, sc = t >> 6;
        alignas(16) _Float16 tmp[16];
        #pragma unroll
        for (int i = 0; i < 16; ++i) tmp[i] = (_Float16)Ls[sc * 16 + i][dd];
        *(f16x8*)&Wot[(size_t)(d0 + dd) * DM + e0 + sc * 16]     = *(f16x8*)&tmp[0];
        *(f16x8*)&Wot[(size_t)(d0 + dd) * DM + e0 + sc * 16 + 8] = *(f16x8*)&tmp[8];
    }
}

// ---------------------------------------------------------------------------
// NEW QKV GEMM: 256x192 tile, BK=32, 512 threads (8 waves = 2M x 4N),
// double-buffered LDS (56 KB -> 2 blocks/CU, 512 blocks = EXACTLY 2/CU, no
// tail), v14-verified sync skeleton:
//   vmcnt(0) [this tile's stages issued a full iter ago -> free] -> barrier
//   [prior readers lgkm-drained before their barrier] -> stage NEXT tile into
//   other buffer [safe: its readers all passed the barrier] -> ds_read 11
//   frags -> lgkm0 + sched_barrier (rule-18) -> 24 MFMA.
// Halves operand re-read traffic vs 128^2 (A-panel read 16x not 24x; 768->448
// MB) and adds cross-block TLP during the (near-free) vmcnt wait.
// XCD-chunked swizzle (512%8==0, m-fastest): each XCD keeps 2 B-panels
// (768 KB) L2-resident; A streams via L3.
// BK=32 staging: chunk = 16 rows x 64 B; lane l covers (row l>>2, phys chunk
// l&3) holding logical chunk (l&3)^((l>>2)&3); read at ((quad)^(c&3))*8.
// Epilogue = verified MODE-1 formulas with nt*16 -> colb&63 generalization.
// ---------------------------------------------------------------------------
__global__ __launch_bounds__(512, 2) void gemm1_kernel(
    const _Float16* __restrict__ A, const _Float16* __restrict__ Bg,
    _Float16* __restrict__ qo, _Float16* __restrict__ ko, _Float16* __restrict__ vto)
{
    const int bid = blockIdx.x;                 // 0..511
    const int swz = (bid & 7) * 64 + (bid >> 3);
    const int m0 = (swz & 31) * 256;            // m-fastest decomposition
    const int n0 = (swz >> 5) * 192;

    __shared__ _Float16 As[2][256 * 32];        // 2 x 16 KB
    __shared__ _Float16 Bs[2][192 * 32];        // 2 x 12 KB

    const int t = threadIdx.x;
    const int lane = t & 63, w = t >> 6;        // 8 waves
    const int quad = lane >> 4, c = lane & 15;
    const int wm = (w & 1) * 128, wn = (w >> 1) * 48;
    const int srow4 = lane >> 2;                // row-in-chunk (16 rows, 4 lanes/row)
    const int sc8 = ((lane & 3) ^ (srow4 & 3)) * 8;   // swizzled source chunk
    const int colsw4 = (quad ^ (c & 3)) * 8;          // read-side chunk offset

    f32x4 acc[8][3];
    #pragma unroll
    for (int i = 0; i < 8; ++i)
        #pragma unroll
        for (int j = 0; j < 3; ++j) acc[i][j] = {0.f, 0.f, 0.f, 0.f};

    // stage one 256x32 A-tile + 192x32 B-tile. Waves 0-3: A (4 instrs each,
    // 16 chunks of 16 rows); waves 4-7: B (3 instrs each, 12 chunks).
    auto stage = [&](int bi, int e0) {
        if (w < 4) {
            #pragma unroll
            for (int j = 0; j < 4; ++j) {
                int ch = w * 4 + j;             // 0..15
                gload_lds16(A + (size_t)(m0 + ch * 16 + srow4) * DM + e0 + sc8,
                            &As[bi][ch * 512]);
            }
        } else {
            #pragma unroll
            for (int j = 0; j < 3; ++j) {
                int ch = (w - 4) * 3 + j;       // 0..11
                gload_lds16(Bg + (size_t)(n0 + ch * 16 + srow4) * DM + e0 + sc8,
                            &Bs[bi][ch * 512]);
            }
        }
    };

    stage(0, 0);
    for (int T = 0; T < 32; ++T) {
        const int bi = T & 1;
        // tile T's stages were issued a full iteration ago -> near-free drain
        asm volatile("s_waitcnt vmcnt(0)" ::: "memory");
        __builtin_amdgcn_s_barrier();           // block-wide: T staged, T-1 reads done
        __builtin_amdgcn_sched_barrier(0);
        if (T < 31) stage(bi ^ 1, (T + 1) * 32);   // readers of bi^1 all passed barrier

        const _Float16* Ap = &As[bi][(wm + c) * 32 + colsw4];
        const _Float16* Bp = &Bs[bi][(wn + c) * 32 + colsw4];
        f16x8 af[8], bf[3];
        #pragma unroll
        for (int mt = 0; mt < 8; ++mt) af[mt] = *(const f16x8*)(Ap + mt * 512);
        #pragma unroll
        for (int nt = 0; nt < 3; ++nt) bf[nt] = *(const f16x8*)(Bp + nt * 512);
        asm volatile("s_waitcnt lgkmcnt(0)" ::: "memory");
        __builtin_amdgcn_sched_barrier(0);      // rule-18: keep MFMA below the drain

        __builtin_amdgcn_s_setprio(1);
        #pragma unroll
        for (int mt = 0; mt < 8; ++mt)
            #pragma unroll
            for (int nt = 0; nt < 3; ++nt)
                acc[mt][nt] = __builtin_amdgcn_mfma_f32_16x16x32_f16(af[mt], bf[nt], acc[mt][nt], 0, 0, 0);
        __builtin_amdgcn_s_setprio(0);
    }

    // ---- epilogue: verified MODE-1 formulas, per-nt 64-col group ----------
    #pragma unroll
    for (int nt = 0; nt < 3; ++nt) {
        const int colb = n0 + wn + nt * 16;     // 16-aligned
        const int g = colb >> 6;                // 0..47
        const int which = g >> 4, hh = g & 15;
        const int dlo = colb & 63;
        if (which == 2) {
            // V -> Vg2 attn-tiled layout (verified R8 formulas)
            #pragma unroll
            for (int mt = 0; mt < 8; ++mt) {
                int tokb = m0 + wm + mt * 16;
                int btok = tokb >> 11;
                int lt   = tokb & (LSEQ - 1);
                int tau  = lt >> 6, sstep = (lt >> 4) & 3;
                int hlw  = quad & 1, jb = 4 * (quad >> 1);
                size_t bhbase = (size_t)(btok * NH + hh) * (32 * 8 * 512);
                int d = dlo + c;
                int m2 = d & 31, dblk = d >> 5;
                f16x4 pk;
                pk[0] = (_Float16)acc[mt][nt][0];
                pk[1] = (_Float16)acc[mt][nt][1];
                pk[2] = (_Float16)acc[mt][nt][2];
                pk[3] = (_Float16)acc[mt][nt][3];
                size_t off = bhbase
                           + ((size_t)(tau * 8 + dblk * 4 + sstep) * 64 + hlw * 32 + m2) * 8 + jb;
                *(f16x4*)&vto[off] = pk;
            }
        } else {
            _Float16* dst = (which == 0) ? qo : ko;
            const float vs = (which == 0) ? 0.18033688011112042f : 1.0f;
            #pragma unroll
            for (int mt = 0; mt < 8; ++mt)
                #pragma unroll
                for (int r = 0; r < 4; ++r) {
                    int tok = m0 + wm + mt * 16 + quad * 4 + r;
                    int b = tok >> 11, l = tok & (LSEQ - 1);
                    int d = dlo + c;
                    dst[((size_t)(b * NH + hh) * LSEQ + l) * HD + d] = (_Float16)(acc[mt][nt][r] * vs);
                }
        }
    }
}

// ---------------------------------------------------------------------------
// GEMM-BT, fp16 MFMA, 128x128 tile, BK=64 (m97-verified). Used for the
// output projection only (MODE 0): out fp32 [M][DM].
// ---------------------------------------------------------------------------
template<int MODE>
__global__ __launch_bounds__(256) void gemm_kernel(
    const _Float16* __restrict__ A, const _Float16* __restrict__ B,
    float* __restrict__ out32)
{
    const int n0 = blockIdx.x * 128, m0 = blockIdx.y * 128;
    __shared__ _Float16 As[128 * 64];   // swizzled [row][chunk^(row&7)]
    __shared__ _Float16 Bs[128 * 64];
    const int t = threadIdx.x;
    const int lane = t & 63, w = t >> 6;
    const int quad = lane >> 4, c = lane & 15;
    const int wm = (w & 1) * 64, wn = (w >> 1) * 64;
    const int srow = lane >> 3;
    const int scol8 = ((lane & 7) ^ (lane >> 3)) * 8;     // swizzled source chunk

    const int colsw = (quad ^ (c & 7)) * 8;
    const _Float16* Ap0 = &As[(wm + c) * 64 + colsw];
    const _Float16* Ap1 = &As[(wm + c) * 64 + (colsw ^ 32)];
    const _Float16* Bp0 = &Bs[(wn + c) * 64 + colsw];
    const _Float16* Bp1 = &Bs[(wn + c) * 64 + (colsw ^ 32)];

    f32x4 acc[4][4];
    #pragma unroll
    for (int i = 0; i < 4; ++i)
        #pragma unroll
        for (int j = 0; j < 4; ++j) acc[i][j] = {0.f, 0.f, 0.f, 0.f};

    for (int e0 = 0; e0 < DM; e0 += 64) {
        __syncthreads();
        #pragma unroll
        for (int j = 0; j < 4; ++j) {
            int ch = w * 4 + j;                 // 16 chunks of 8 rows x 128 B
            gload_lds16(A + (size_t)(m0 + ch * 8 + srow) * DM + e0 + scol8, As + ch * 512);
            gload_lds16(B + (size_t)(n0 + ch * 8 + srow) * DM + e0 + scol8, Bs + ch * 512);
        }
        __syncthreads();                        // drains vmcnt -> LDS valid
        #pragma unroll
        for (int kc = 0; kc < 2; ++kc) {
            const _Float16* Ap = kc ? Ap1 : Ap0;
            const _Float16* Bp = kc ? Bp1 : Bp0;
            f16x8 af[4], bf[4];
            #pragma unroll
            for (int mt = 0; mt < 4; ++mt) af[mt] = *(const f16x8*)(Ap + mt * 1024);
            #pragma unroll
            for (int nt = 0; nt < 4; ++nt) bf[nt] = *(const f16x8*)(Bp + nt * 1024);
            #pragma unroll
            for (int mt = 0; mt < 4; ++mt)
                #pragma unroll
                for (int nt = 0; nt < 4; ++nt)
                    acc[mt][nt] = __builtin_amdgcn_mfma_f32_16x16x32_f16(af[mt], bf[nt], acc[mt][nt], 0, 0, 0);
        }
    }

    #pragma unroll
    for (int mt = 0; mt < 4; ++mt)
        #pragma unroll
        for (int nt = 0; nt < 4; ++nt)
            #pragma unroll
            for (int r = 0; r < 4; ++r) {
                int row = m0 + wm + mt * 16 + quad * 4 + r;
                int col = n0 + wn + nt * 16 + c;
                out32[(size_t)row * DM + col] = acc[mt][nt][r];
            }
}

// ---------------------------------------------------------------------------
// Flash attention v14 (byte-exact R8/R10 — verified 87-89 us, no spills).
// ---------------------------------------------------------------------------
__global__ __launch_bounds__(256, 4) void attn_kernel(
    const _Float16* __restrict__ Qg, const _Float16* __restrict__ Kg,
    const _Float16* __restrict__ Vtg, _Float16* __restrict__ concat)
{
    const int bh = blockIdx.x;
    const int q0 = blockIdx.y * 128;
    const int b = bh >> 4, head = bh & (NH - 1);
    __shared__ _Float16 Ks[2][64 * 64];     // [s][d] swizzled, double-buffered
    const int t = threadIdx.x;
    const int lane = t & 63, w = t >> 6;           // w in {0..3}
    const int m = lane & 31, hl = lane >> 5;       // m = q-row (lane-local), hl = half
    const int srow = lane >> 3;
    const int scol8 = ((lane & 7) ^ (lane >> 3)) * 8;     // swizzled source chunk

    // Q fragments: rows q0 + w*32 + m, k = kstep*16 + hl*8 + j  (B-operand)
    f16x8 qf[4];
    #pragma unroll
    for (int kstep = 0; kstep < 4; ++kstep)
        qf[kstep] = *(const f16x8*)&Qg[((size_t)bh * LSEQ + q0 + w * 32 + m) * HD + kstep * 16 + hl * 8];

    f32x16 o[2];
    #pragma unroll
    for (int i = 0; i < 16; ++i) { o[0][i] = 0.f; o[1][i] = 0.f; }
    float lp = 0.f;
    const hf16x2 ones2 = {(__fp16)1.0f, (__fp16)1.0f};

    // stage one 64-row K tile into buffer bi (2 gload_lds per wave)
    auto stage = [&](int bi, int s0n) {
        #pragma unroll
        for (int j = 0; j < 2; ++j) {
            int ch = w * 2 + j;                 // 8 chunks of 8 rows x 128 B each
            gload_lds16(Kg + ((size_t)bh * LSEQ + s0n + ch * 8 + srow) * HD + scol8, &Ks[bi][ch * 512]);
        }
    };

    // V register tile: Vg2 per-tile 8KB; instr q reads lane-linear 1KB.
    const _Float16* Vbase = Vtg + (size_t)bh * (32 * 8 * 512) + (size_t)lane * 8;
    f16x8 vf[8];
    auto loadV = [&](int tile) {
        const _Float16* p = Vbase + (size_t)tile * 4096;
        #pragma unroll
        for (int q = 0; q < 8; ++q)
            vf[q] = *(const f16x8*)(p + q * 512);
    };

    constexpr int NT = LSEQ / 64;   // 32 tiles
    stage(0, 0);        // K(0): 2 vm ops
    loadV(0);           // V(0): 8 vm ops
    int cur = 0;

    for (int tt = 0; tt < NT; ++tt) {
        // in flight: K(tt)[2, oldest] + V(tt)[8] -> drain K(tt) only
        asm volatile("s_waitcnt vmcnt(8)" ::: "memory");
        __builtin_amdgcn_s_barrier();          // all waves: compute(t-1) done, K(t) staged
        __builtin_amdgcn_sched_barrier(0);

        if (tt + 1 < NT) stage(cur ^ 1, (tt + 1) * 64);   // overwrite t-1's buffer (safe)

        const _Float16* Kb = &Ks[cur][0];

        // ---- QK^T + softmax; P kept in NATIVE register order ---------------
        f16x8 pf[4];                            // A-operand P frags, sstep 0..3
        #pragma unroll
        for (int sblk = 0; sblk < 2; ++sblk) {
            const int rr = sblk * 32 + m;       // K row for this lane
            const int rx = rr & 7;
            const _Float16* Krow = Kb + rr * 64;
            f32x16 sT;
            #pragma unroll
            for (int i = 0; i < 16; ++i) sT[i] = 0.f;
            __builtin_amdgcn_s_setprio(1);
            #pragma unroll
            for (int kstep = 0; kstep < 4; ++kstep) {
                f16x8 kf = *(const f16x8*)(Krow + (((kstep * 2 + hl) ^ rx) * 8));
                sT = __builtin_amdgcn_mfma_f32_32x32x16_f16(kf, qf[kstep], sT, 0, 0, 0);
            }
            __builtin_amdgcn_s_setprio(0);
            union { unsigned int u[4]; f16x8 v; } P0, P1;
            #pragma unroll
            for (int q = 0; q < 8; ++q) {
                float e0 = __builtin_amdgcn_exp2f(sT[2 * q]);
                float e1 = __builtin_amdgcn_exp2f(sT[2 * q + 1]);
                union { hf16x2 h; unsigned int u; } uu;
                uu.h = __builtin_amdgcn_cvt_pkrtz(e0, e1);
                lp = __builtin_amdgcn_fdot2(uu.h, ones2, lp, false);
                if (q < 4) P0.u[q] = uu.u; else P1.u[q - 4] = uu.u;
            }
            pf[sblk * 2 + 0] = P0.v;
            pf[sblk * 2 + 1] = P1.v;
        }

        // ---- O += P V.  vf holds tile tt (loaded last iter; compiler waits) -
        __builtin_amdgcn_s_setprio(1);
        #pragma unroll
        for (int dblk = 0; dblk < 2; ++dblk)
            #pragma unroll
            for (int sstep = 0; sstep < 4; ++sstep)
                o[dblk] = __builtin_amdgcn_mfma_f32_32x32x16_f16(pf[sstep], vf[dblk * 4 + sstep], o[dblk], 0, 0, 0);
        __builtin_amdgcn_s_setprio(0);

        if (tt + 1 < NT) loadV(tt + 1);        // WAR on vf: issues after PV reads

        asm volatile("s_waitcnt lgkmcnt(0)" ::: "memory");
        __builtin_amdgcn_sched_barrier(0);
        cur ^= 1;
    }

    // lp: lane holds half the s-sum for row m; combine halves
    lp += __shfl_xor(lp, 32);

    // epilogue: row(reg) = (rg&3) + 8*(rg>>2) + 4*hl
    #pragma unroll
    for (int rg = 0; rg < 16; ++rg) {
        const int mrow = (rg & 3) + 8 * (rg >> 2) + 4 * hl;
        const float inv = 1.f / __shfl(lp, mrow);
        const int row = q0 + w * 32 + mrow;
        #pragma unroll
        for (int dblk = 0; dblk < 2; ++dblk)
            concat[((size_t)b * LSEQ + row) * DM + head * HD + dblk * 32 + m] =
                (_Float16)(o[dblk][rg] * inv);
    }
}

// ---------------------------------------------------------------------------
extern "C" void kernel_launch(void* const* d_in, const int* in_sizes, int n_in,
                              void* d_out, int out_size, void* d_ws, size_t ws_size,
                              hipStream_t stream)
{
    (void)in_sizes; (void)n_in; (void)out_size; (void)ws_size;

    const float* x  = (const float*)d_in[0];
    const float* Wq = (const float*)d_in[1];
    const float* Wk = (const float*)d_in[2];
    const float* Wv = (const float*)d_in[3];
    const float* Wo = (const float*)d_in[4];
    float* out = (float*)d_out;

    const size_t XE = (size_t)NTOK * DM;          // 8388608
    const size_t WQKV = (size_t)3 * NH * HD * DM; // 3145728
    _Float16* xh  = (_Float16*)d_ws;
    _Float16* WtA = xh + XE;
    _Float16* Wot = WtA + WQKV;
    _Float16* q   = Wot + (size_t)DM * DM;
    _Float16* k   = q + XE;
    _Float16* vt  = k + XE;
    _Float16* cc  = vt + XE;

    prep_kernel<<<9216, 256, 0, stream>>>(x, Wq, Wk, Wv, Wo, xh, WtA, Wot);

    gemm1_kernel<<<512, 512, 0, stream>>>(xh, WtA, q, k, vt);
    attn_kernel<<<dim3(64, LSEQ / 128), 256, 0, stream>>>(q, k, vt, cc);
    gemm_kernel<0><<<dim3(8, 64), 256, 0, stream>>>(cc, Wot, out);
}

// Round 12
// 266.200 us; speedup vs baseline: 1.0820x; 1.0820x over previous
//
#include <hip/hip_runtime.h>

#define BATCH 4
#define LSEQ  2048
#define DM    1024
#define NH    16
#define HD    64
#define NTOK  (BATCH * LSEQ)

typedef _Float16 f16x8 __attribute__((ext_vector_type(8)));
typedef _Float16 f16x4 __attribute__((ext_vector_type(4)));
typedef __fp16   hf16x2 __attribute__((ext_vector_type(2)));
typedef float    f32x4 __attribute__((ext_vector_type(4)));
typedef float    f32x16 __attribute__((ext_vector_type(16)));

typedef __attribute__((address_space(1))) const unsigned int GU32;
typedef __attribute__((address_space(3))) unsigned int LU32;

// async 16B/lane global->LDS. lptr must be wave-uniform; HW dest = lptr + lane*16.
__device__ __forceinline__ void gload_lds16(const _Float16* g, _Float16* l)
{
    __builtin_amdgcn_global_load_lds(
        (GU32*)(unsigned long long)g,
        (LU32*)(unsigned int)(unsigned long long)l, 16, 0, 0);
}

// XOR-swizzle: tile rows of 8 chunks (chunk = 16 B). Physical chunk p of row r
// holds logical chunk p ^ (r & 7) (lane i stages logical chunk (i&7)^(i>>3)).

// ---------------------------------------------------------------------------
// Fused prep: one launch, three phases by linear block-id range (R10 verified).
//   [0, 8192)        : x fp32 -> fp16
//   [8192, 8960)     : Wq/Wk/Wv transpose+cast
//   [8960, 9216)     : Wo transpose+cast
// ---------------------------------------------------------------------------
__global__ __launch_bounds__(256) void prep_kernel(
    const float* __restrict__ x,
    const float* __restrict__ Wq, const float* __restrict__ Wk,
    const float* __restrict__ Wv, const float* __restrict__ Wo,
    _Float16* __restrict__ xh, _Float16* __restrict__ WtA,
    _Float16* __restrict__ Wot)
{
    const int bid = blockIdx.x;
    const int t = threadIdx.x;

    if (bid < 8192) {                       // ---- cvt phase ----
        int i = bid * 256 + t;
        float4 v = ((const float4*)x)[i];
        f16x4 h;
        h[0] = (_Float16)v.x; h[1] = (_Float16)v.y; h[2] = (_Float16)v.z; h[3] = (_Float16)v.w;
        ((f16x4*)xh)[i] = h;
        return;
    }

    __shared__ float Ls[64][65];

    if (bid < 8960) {                       // ---- Wq/Wk/Wv transpose ----
        const int idx = bid - 8192;
        const int z = idx >> 4;             // 0..47
        const int which = z >> 4, h = z & 15;
        const float* __restrict__ src =
            ((which == 0) ? Wq : (which == 1) ? Wk : Wv) + (size_t)h * DM * HD;
        _Float16* __restrict__ d = WtA + (size_t)z * DM * HD;
        const int e0 = (idx & 15) * 64;
        #pragma unroll
        for (int j = 0; j < 4; ++j) {
            int cidx = t + j * 256;
            int row = cidx >> 4, col4 = (cidx & 15) * 4;
            float4 v = *(const float4*)&src[(size_t)(e0 + row) * HD + col4];
            Ls[row][col4] = v.x; Ls[row][col4+1] = v.y; Ls[row][col4+2] = v.z; Ls[row][col4+3] = v.w;
        }
        __syncthreads();
        const int dd = t & 63, sc = t >> 6;
        alignas(16) _Float16 tmp[16];
        #pragma unroll
        for (int i = 0; i < 16; ++i) tmp[i] = (_Float16)Ls[sc * 16 + i][dd];
        *(f16x8*)&d[(size_t)dd * DM + e0 + sc * 16]     = *(f16x8*)&tmp[0];
        *(f16x8*)&d[(size_t)dd * DM + e0 + sc * 16 + 8] = *(f16x8*)&tmp[8];
        return;
    }

    {                                       // ---- Wo transpose ----
        const int idx = bid - 8960;
        const int d0 = (idx & 15) * 64, e0 = (idx >> 4) * 64;
        #pragma unroll
        for (int j = 0; j < 4; ++j) {
            int cidx = t + j * 256;
            int row = cidx >> 4, col4 = (cidx & 15) * 4;
            float4 v = *(const float4*)&Wo[(size_t)(e0 + row) * DM + d0 + col4];
            Ls[row][col4] = v.x; Ls[row][col4+1] = v.y; Ls[row][col4+2] = v.z; Ls[row][col4+3] = v.w;
        }
        __syncthreads();
        const int dd = t & 63, sc = t >> 6;
        alignas(16) _Float16 tmp[16];
        #pragma unroll
        for (int i = 0; i < 16; ++i) tmp[i] = (_Float16)Ls[sc * 16 + i][dd];
        *(f16x8*)&Wot[(size_t)(d0 + dd) * DM + e0 + sc * 16]     = *(f16x8*)&tmp[0];
        *(f16x8*)&Wot[(size_t)(d0 + dd) * DM + e0 + sc * 16 + 8] = *(f16x8*)&tmp[8];
    }
}

// ---------------------------------------------------------------------------
// GEMM-BT, fp16 MFMA, 128x128 tile, BK=64, global_load_lds + XOR swizzle.
// (R11 lesson: 128^2 is the measured tile-space optimum for this 2-barrier
// structure — 256x192/BK=32 with dbuf+counted-vmcnt was 17 us SLOWER: the
// drain is only one short compute-phase after issue, and 2 blocks/CU has no
// TLP to cover it.)
// MODE 0: out fp32 [M][DM].
// MODE 1: q [bh][l][d] (scaled), k [bh][l][d], v -> attn-tiled Vg2 layout:
//   Vg2[bh][tau][q=dblk*4+sstep][lane=m+32*hl][j] =
//     storedVt[bh][dblk*32+m][64*tau + 16*sstep + 8*hl + j]
//   (storedVt carries the v13-verified s-permutation: stored s-index
//    l = tokb + 8*(quad&1) + 4*(quad>>1) + r).
// ---------------------------------------------------------------------------
template<int MODE>
__global__ __launch_bounds__(256) void gemm_kernel(
    const _Float16* __restrict__ A, const _Float16* __restrict__ B,
    float* __restrict__ out32,
    _Float16* __restrict__ qo, _Float16* __restrict__ ko, _Float16* __restrict__ vto)
{
    const int n0 = blockIdx.x * 128, m0 = blockIdx.y * 128;
    __shared__ _Float16 As[128 * 64];   // swizzled [row][chunk^(row&7)]
    __shared__ _Float16 Bs[128 * 64];
    const int t = threadIdx.x;
    const int lane = t & 63, w = t >> 6;
    const int quad = lane >> 4, c = lane & 15;
    const int wm = (w & 1) * 64, wn = (w >> 1) * 64;
    const int srow = lane >> 3;
    const int scol8 = ((lane & 7) ^ (lane >> 3)) * 8;     // swizzled source chunk

    // hoisted fragment base pointers (kc=0 / kc=1)
    const int colsw = (quad ^ (c & 7)) * 8;
    const _Float16* Ap0 = &As[(wm + c) * 64 + colsw];
    const _Float16* Ap1 = &As[(wm + c) * 64 + (colsw ^ 32)];
    const _Float16* Bp0 = &Bs[(wn + c) * 64 + colsw];
    const _Float16* Bp1 = &Bs[(wn + c) * 64 + (colsw ^ 32)];

    f32x4 acc[4][4];
    #pragma unroll
    for (int i = 0; i < 4; ++i)
        #pragma unroll
        for (int j = 0; j < 4; ++j) acc[i][j] = {0.f, 0.f, 0.f, 0.f};

    for (int e0 = 0; e0 < DM; e0 += 64) {
        __syncthreads();
        #pragma unroll
        for (int j = 0; j < 4; ++j) {
            int ch = w * 4 + j;                 // 16 chunks of 8 rows x 128 B
            gload_lds16(A + (size_t)(m0 + ch * 8 + srow) * DM + e0 + scol8, As + ch * 512);
            gload_lds16(B + (size_t)(n0 + ch * 8 + srow) * DM + e0 + scol8, Bs + ch * 512);
        }
        __syncthreads();                        // drains vmcnt -> LDS valid
        #pragma unroll
        for (int kc = 0; kc < 2; ++kc) {
            const _Float16* Ap = kc ? Ap1 : Ap0;
            const _Float16* Bp = kc ? Bp1 : Bp0;
            f16x8 af[4], bf[4];
            #pragma unroll
            for (int mt = 0; mt < 4; ++mt) af[mt] = *(const f16x8*)(Ap + mt * 1024);
            #pragma unroll
            for (int nt = 0; nt < 4; ++nt) bf[nt] = *(const f16x8*)(Bp + nt * 1024);
            #pragma unroll
            for (int mt = 0; mt < 4; ++mt)
                #pragma unroll
                for (int nt = 0; nt < 4; ++nt)
                    acc[mt][nt] = __builtin_amdgcn_mfma_f32_16x16x32_f16(af[mt], bf[nt], acc[mt][nt], 0, 0, 0);
        }
    }

    if (MODE == 0) {
        #pragma unroll
        for (int mt = 0; mt < 4; ++mt)
            #pragma unroll
            for (int nt = 0; nt < 4; ++nt)
                #pragma unroll
                for (int r = 0; r < 4; ++r) {
                    int row = m0 + wm + mt * 16 + quad * 4 + r;
                    int col = n0 + wn + nt * 16 + c;
                    out32[(size_t)row * DM + col] = acc[mt][nt][r];
                }
    } else {
        const int mi = (n0 + wn) >> 6;            // 0..47, wave-uniform
        const int which = mi >> 4, hh = mi & 15;
        if (which == 2) {
            // V -> Vg2 attn-tiled layout (verified R8 formulas).
            #pragma unroll
            for (int mt = 0; mt < 4; ++mt) {
                int tokb = m0 + wm + mt * 16;           // 16-aligned block base
                int btok = tokb >> 11;
                int lt   = tokb & (LSEQ - 1);
                int tau  = lt >> 6, sstep = (lt >> 4) & 3;
                int hlw  = quad & 1, jb = 4 * (quad >> 1);
                size_t bhbase = (size_t)(btok * NH + hh) * (32 * 8 * 512);
                #pragma unroll
                for (int nt = 0; nt < 4; ++nt) {
                    int d = nt * 16 + c;
                    int m2 = d & 31, dblk = d >> 5;
                    f16x4 pk;
                    pk[0] = (_Float16)acc[mt][nt][0];
                    pk[1] = (_Float16)acc[mt][nt][1];
                    pk[2] = (_Float16)acc[mt][nt][2];
                    pk[3] = (_Float16)acc[mt][nt][3];
                    size_t off = bhbase
                               + ((size_t)(tau * 8 + dblk * 4 + sstep) * 64 + hlw * 32 + m2) * 8 + jb;
                    *(f16x4*)&vto[off] = pk;
                }
            }
        } else {
            _Float16* dst = (which == 0) ? qo : ko;
            // q pre-scaled by 1/sqrt(64)*log2(e) so attention can use raw exp2
            const float vs = (which == 0) ? 0.18033688011112042f : 1.0f;
            #pragma unroll
            for (int mt = 0; mt < 4; ++mt)
                #pragma unroll
                for (int nt = 0; nt < 4; ++nt)
                    #pragma unroll
                    for (int r = 0; r < 4; ++r) {
                        int tok = m0 + wm + mt * 16 + quad * 4 + r;
                        int b = tok >> 11, l = tok & (LSEQ - 1);
                        int d = nt * 16 + c;
                        dst[((size_t)(b * NH + hh) * LSEQ + l) * HD + d] = (_Float16)(acc[mt][nt][r] * vs);
                    }
        }
    }
}

// ---------------------------------------------------------------------------
// Flash attention v14 (byte-exact R8/R10 — verified 87-90 us, no spills).
// K in LDS dbuf (16 KB), V direct-to-register from attn-tiled Vg2 (1KB
// lane-linear loads), one barrier per tile:
//   vmcnt(8) [K(t) landed; V(t) free-flying] -> barrier -> stage K(t+1) ->
//   QK^T -> PV(vf) -> loadV(t+1) (WAR after PV) -> lgkm drain -> sched fence.
// R9 lesson: do NOT widen the scheduling region across tiles — the doubled
// live state spills to scratch (WRITE_SIZE 16->101 MB, attn +30 us).
// 32x32x16 MFMA, native-P k-order (verified v12/v13), fdot2 lp, setprio.
// XCD-aware: linear id == bh (mod 8) -> one head's K/V stays in its L2.
// No max-subtraction; q pre-scaled by 0.125*log2e -> P = exp2(S) raw.
// ---------------------------------------------------------------------------
__global__ __launch_bounds__(256, 4) void attn_kernel(
    const _Float16* __restrict__ Qg, const _Float16* __restrict__ Kg,
    const _Float16* __restrict__ Vtg, _Float16* __restrict__ concat)
{
    const int bh = blockIdx.x;
    const int q0 = blockIdx.y * 128;
    const int b = bh >> 4, head = bh & (NH - 1);
    __shared__ _Float16 Ks[2][64 * 64];     // [s][d] swizzled, double-buffered
    const int t = threadIdx.x;
    const int lane = t & 63, w = t >> 6;           // w in {0..3}
    const int m = lane & 31, hl = lane >> 5;       // m = q-row (lane-local), hl = half
    const int srow = lane >> 3;
    const int scol8 = ((lane & 7) ^ (lane >> 3)) * 8;     // swizzled source chunk

    // Q fragments: rows q0 + w*32 + m, k = kstep*16 + hl*8 + j  (B-operand)
    f16x8 qf[4];
    #pragma unroll
    for (int kstep = 0; kstep < 4; ++kstep)
        qf[kstep] = *(const f16x8*)&Qg[((size_t)bh * LSEQ + q0 + w * 32 + m) * HD + kstep * 16 + hl * 8];

    f32x16 o[2];
    #pragma unroll
    for (int i = 0; i < 16; ++i) { o[0][i] = 0.f; o[1][i] = 0.f; }
    float lp = 0.f;
    const hf16x2 ones2 = {(__fp16)1.0f, (__fp16)1.0f};

    // stage one 64-row K tile into buffer bi (2 gload_lds per wave)
    auto stage = [&](int bi, int s0n) {
        #pragma unroll
        for (int j = 0; j < 2; ++j) {
            int ch = w * 2 + j;                 // 8 chunks of 8 rows x 128 B each
            gload_lds16(Kg + ((size_t)bh * LSEQ + s0n + ch * 8 + srow) * HD + scol8, &Ks[bi][ch * 512]);
        }
    };

    // V register tile: Vg2 per-tile 8KB; instr q reads lane-linear 1KB.
    const _Float16* Vbase = Vtg + (size_t)bh * (32 * 8 * 512) + (size_t)lane * 8;
    f16x8 vf[8];
    auto loadV = [&](int tile) {
        const _Float16* p = Vbase + (size_t)tile * 4096;
        #pragma unroll
        for (int q = 0; q < 8; ++q)
            vf[q] = *(const f16x8*)(p + q * 512);
    };

    constexpr int NT = LSEQ / 64;   // 32 tiles
    stage(0, 0);        // K(0): 2 vm ops
    loadV(0);           // V(0): 8 vm ops
    int cur = 0;

    for (int tt = 0; tt < NT; ++tt) {
        // in flight: K(tt)[2, oldest] + V(tt)[8] -> drain K(tt) only
        asm volatile("s_waitcnt vmcnt(8)" ::: "memory");
        __builtin_amdgcn_s_barrier();          // all waves: compute(t-1) done, K(t) staged
        __builtin_amdgcn_sched_barrier(0);

        if (tt + 1 < NT) stage(cur ^ 1, (tt + 1) * 64);   // overwrite t-1's buffer (safe)

        const _Float16* Kb = &Ks[cur][0];

        // ---- QK^T + softmax; P kept in NATIVE register order ---------------
        f16x8 pf[4];                            // A-operand P frags, sstep 0..3
        #pragma unroll
        for (int sblk = 0; sblk < 2; ++sblk) {
            const int rr = sblk * 32 + m;       // K row for this lane
            const int rx = rr & 7;
            const _Float16* Krow = Kb + rr * 64;
            f32x16 sT;
            #pragma unroll
            for (int i = 0; i < 16; ++i) sT[i] = 0.f;
            __builtin_amdgcn_s_setprio(1);
            #pragma unroll
            for (int kstep = 0; kstep < 4; ++kstep) {
                f16x8 kf = *(const f16x8*)(Krow + (((kstep * 2 + hl) ^ rx) * 8));
                sT = __builtin_amdgcn_mfma_f32_32x32x16_f16(kf, qf[kstep], sT, 0, 0, 0);
            }
            __builtin_amdgcn_s_setprio(0);
            union { unsigned int u[4]; f16x8 v; } P0, P1;
            #pragma unroll
            for (int q = 0; q < 8; ++q) {
                float e0 = __builtin_amdgcn_exp2f(sT[2 * q]);
                float e1 = __builtin_amdgcn_exp2f(sT[2 * q + 1]);
                union { hf16x2 h; unsigned int u; } uu;
                uu.h = __builtin_amdgcn_cvt_pkrtz(e0, e1);
                lp = __builtin_amdgcn_fdot2(uu.h, ones2, lp, false);
                if (q < 4) P0.u[q] = uu.u; else P1.u[q - 4] = uu.u;
            }
            pf[sblk * 2 + 0] = P0.v;
            pf[sblk * 2 + 1] = P1.v;
        }

        // ---- O += P V.  vf holds tile tt (loaded last iter; compiler waits) -
        __builtin_amdgcn_s_setprio(1);
        #pragma unroll
        for (int dblk = 0; dblk < 2; ++dblk)
            #pragma unroll
            for (int sstep = 0; sstep < 4; ++sstep)
                o[dblk] = __builtin_amdgcn_mfma_f32_32x32x16_f16(pf[sstep], vf[dblk * 4 + sstep], o[dblk], 0, 0, 0);
        __builtin_amdgcn_s_setprio(0);

        if (tt + 1 < NT) loadV(tt + 1);        // WAR on vf: issues after PV reads

        // Drain own LDS reads BEFORE next barrier (rule-#18 hazard guard);
        // fence pins loads/mfma on this side of the loop boundary.
        asm volatile("s_waitcnt lgkmcnt(0)" ::: "memory");
        __builtin_amdgcn_sched_barrier(0);
        cur ^= 1;
    }

    // lp: lane holds half the s-sum for row m; combine halves
    lp += __shfl_xor(lp, 32);

    // epilogue: row(reg) = (rg&3) + 8*(rg>>2) + 4*hl
    #pragma unroll
    for (int rg = 0; rg < 16; ++rg) {
        const int mrow = (rg & 3) + 8 * (rg >> 2) + 4 * hl;
        const float inv = 1.f / __shfl(lp, mrow);
        const int row = q0 + w * 32 + mrow;
        #pragma unroll
        for (int dblk = 0; dblk < 2; ++dblk)
            concat[((size_t)b * LSEQ + row) * DM + head * HD + dblk * 32 + m] =
                (_Float16)(o[dblk][rg] * inv);
    }
}

// ---------------------------------------------------------------------------
extern "C" void kernel_launch(void* const* d_in, const int* in_sizes, int n_in,
                              void* d_out, int out_size, void* d_ws, size_t ws_size,
                              hipStream_t stream)
{
    (void)in_sizes; (void)n_in; (void)out_size; (void)ws_size;

    const float* x  = (const float*)d_in[0];
    const float* Wq = (const float*)d_in[1];
    const float* Wk = (const float*)d_in[2];
    const float* Wv = (const float*)d_in[3];
    const float* Wo = (const float*)d_in[4];
    float* out = (float*)d_out;

    const size_t XE = (size_t)NTOK * DM;          // 8388608
    const size_t WQKV = (size_t)3 * NH * HD * DM; // 3145728
    _Float16* xh  = (_Float16*)d_ws;
    _Float16* WtA = xh + XE;
    _Float16* Wot = WtA + WQKV;
    _Float16* q   = Wot + (size_t)DM * DM;
    _Float16* k   = q + XE;
    _Float16* vt  = k + XE;
    _Float16* cc  = vt + XE;

    prep_kernel<<<9216, 256, 0, stream>>>(x, Wq, Wk, Wv, Wo, xh, WtA, Wot);

    gemm_kernel<1><<<dim3(24, 64), 256, 0, stream>>>(xh, WtA, nullptr, q, k, vt);
    attn_kernel<<<dim3(64, LSEQ / 128), 256, 0, stream>>>(q, k, vt, cc);
    gemm_kernel<0><<<dim3(8, 64), 256, 0, stream>>>(cc, Wot, out, nullptr, nullptr, nullptr);
}